// Round 5
// baseline (168.122 us; speedup 1.0000x reference)
//
#include <hip/hip_runtime.h>
#include <hip/hip_bf16.h>
#include <stdint.h>

#define NN 2048
#define LOG2NN 11
#define GK 2048
#define GNC 2048

typedef __bf16 bf16x8 __attribute__((ext_vector_type(8)));
typedef float f32x4 __attribute__((ext_vector_type(4)));

// round-to-nearest-even f32 -> bf16 bits
__device__ __forceinline__ ushort f2bf(float f) {
  uint32_t x = __float_as_uint(f);
  uint32_t r = (x + 0x7fffu + ((x >> 16) & 1u)) >> 16;
  return (ushort)r;
}

// ---------------------------------------------------------------- prep (fused)
// blocks [0,2048): transpose W1/W2 f32 -> bf16^T (64x64 tiles)
// blocks [2048,6144): x f32 -> bf16 (8 elems/thread)
// block 6144: zero hist/uW/ecnt
// blocks [6145,14337): zero out (split-K GEMM accumulates atomically into it)
__global__ __launch_bounds__(256) void prep_kernel(
    const float* __restrict__ W1, const float* __restrict__ W2,
    ushort* __restrict__ WT, ushort* __restrict__ W2T,
    const float* __restrict__ x, ushort* __restrict__ xb,
    int* __restrict__ hist, float* __restrict__ uW, int* __restrict__ ecnt,
    float4* __restrict__ out4) {
  __shared__ float tile[64][65];
  const int bid = blockIdx.x;
  const int t = threadIdx.x;
  if (bid < 2048) {  // transpose: out[c][r] = (bf16) in[r][c]
    const int m = bid >> 10;            // 0 = W1, 1 = W2
    const int rem = bid & 1023;
    const int r0 = (rem >> 5) * 64, c0 = (rem & 31) * 64;
    const float* in = m ? W2 : W1;
    ushort* out = m ? W2T : WT;
    const int tx = t & 15, ty = t >> 4;
#pragma unroll
    for (int i = 0; i < 4; ++i) {
      int r = i * 16 + ty;
      float4 v = *reinterpret_cast<const float4*>(&in[(size_t)(r0 + r) * NN + c0 + tx * 4]);
      tile[r][tx * 4 + 0] = v.x;
      tile[r][tx * 4 + 1] = v.y;
      tile[r][tx * 4 + 2] = v.z;
      tile[r][tx * 4 + 3] = v.w;
    }
    __syncthreads();
#pragma unroll
    for (int i = 0; i < 4; ++i) {
      int oc = i * 16 + ty;  // output row = original col
      ushort4 o;
      o.x = f2bf(tile[tx * 4 + 0][oc]);
      o.y = f2bf(tile[tx * 4 + 1][oc]);
      o.z = f2bf(tile[tx * 4 + 2][oc]);
      o.w = f2bf(tile[tx * 4 + 3][oc]);
      *reinterpret_cast<ushort4*>(&out[(size_t)(c0 + oc) * NN + r0 + tx * 4]) = o;
    }
  } else if (bid < 6144) {  // x f32 -> bf16
    int i = (bid - 2048) * 256 + t;  // 8 floats each
    const float4* in4 = reinterpret_cast<const float4*>(x);
    float4 a = in4[2 * i];
    float4 b = in4[2 * i + 1];
    uint4 o;
    o.x = (uint32_t)f2bf(a.x) | ((uint32_t)f2bf(a.y) << 16);
    o.y = (uint32_t)f2bf(a.z) | ((uint32_t)f2bf(a.w) << 16);
    o.z = (uint32_t)f2bf(b.x) | ((uint32_t)f2bf(b.y) << 16);
    o.w = (uint32_t)f2bf(b.z) | ((uint32_t)f2bf(b.w) << 16);
    reinterpret_cast<uint4*>(xb)[i] = o;
  } else if (bid == 6144) {  // init
#pragma unroll
    for (int j = 0; j < 8; ++j) {
      hist[t * 8 + j] = 0;
      uW[t * 8 + j] = 0.f;
    }
    if (t == 0) *ecnt = 0;
  } else {  // zero out: 8192 blocks x 256 threads x 16B = 33.55 MB
    int i = (bid - 6145) * 256 + t;
    out4[i] = make_float4(0.f, 0.f, 0.f, 0.f);
  }
}

// ---------------------------------------------------------------- softmax + hist (fused)
__device__ __forceinline__ int lower_bound32(const int* __restrict__ a, int n, int v) {
  int lo = 0, hi = n;
  while (lo < hi) {
    int mid = (lo + hi) >> 1;
    if (a[mid] < v) lo = mid + 1; else hi = mid;
  }
  return lo;
}

// wave w of block b handles row r = b*4+w: segmented softmax over the sorted
// edge list; per-edge probs -> vals[], diag, empty flag, and hist[c] atomics.
__global__ __launch_bounds__(256) void softmax_hist_kernel(
    const int* __restrict__ idx, const float* __restrict__ e, int nnz,
    float* __restrict__ vals, float* __restrict__ diag, int* __restrict__ empty,
    int* __restrict__ ecnt, int* __restrict__ hist) {
  const int w = threadIdx.x >> 6, lane = threadIdx.x & 63;
  const int r = blockIdx.x * 4 + w;
  int lo = lower_bound32(idx, nnz, r << LOG2NN);
  int hi = lower_bound32(idx, nnz, (r + 1) << LOG2NN);
  if (hi <= lo) {  // empty row: softmax of all-equal NEG -> uniform 1/NN
    if (lane == 0) { diag[r] = 1.0f / NN; empty[r] = 1; atomicAdd(ecnt, 1); }
    return;
  }
  float m = -3.0e38f;
  for (int j = lo + lane; j < hi; j += 64) m = fmaxf(m, e[j]);
#pragma unroll
  for (int s = 32; s >= 1; s >>= 1) m = fmaxf(m, __shfl_xor(m, s));
  float sum = 0.f;
  for (int j = lo + lane; j < hi; j += 64) sum += expf(e[j] - m);
#pragma unroll
  for (int s = 32; s >= 1; s >>= 1) sum += __shfl_xor(sum, s);
  float inv = 1.0f / sum;
  float dv = 0.f;
  for (int j = lo + lane; j < hi; j += 64) {
    float v = expf(e[j] - m) * inv;
    vals[j] = v;
    int c = idx[j] & (NN - 1);
    if (c == r) dv = v;
    else atomicAdd(&hist[c], 1);
  }
#pragma unroll
  for (int s = 32; s >= 1; s >>= 1) dv += __shfl_xor(dv, s);
  if (lane == 0) { diag[r] = dv; empty[r] = 0; }
}

// ---------------------------------------------------------------- scan + uw (fused)
// block 0, lanes 0-63: exclusive prefix sum of hist[2048] (32 elems/lane +
// wave shfl-scan). blocks 1..8: uW (dead unless an empty row exists).
__global__ __launch_bounds__(256) void scan_uw_kernel(
    const int* __restrict__ hist, int* __restrict__ base, int* __restrict__ cursor,
    const float* __restrict__ W2, const int* __restrict__ empty,
    const int* __restrict__ ecnt, float* __restrict__ uW) {
  if (blockIdx.x == 0) {
    const int l = threadIdx.x;
    if (l >= 64) return;
    int vals[32], pre[32];
    int run = 0;
#pragma unroll
    for (int j = 0; j < 32; ++j) {
      vals[j] = hist[l * 32 + j];
      pre[j] = run;
      run += vals[j];
    }
    int tot = run, inc = run;
#pragma unroll
    for (int s = 1; s < 64; s <<= 1) {
      int o = __shfl_up(inc, s);
      if (l >= s) inc += o;
    }
    int excl = inc - tot;
#pragma unroll
    for (int j = 0; j < 32; ++j) {
      int b = excl + pre[j];
      base[l * 32 + j] = b;
      cursor[l * 32 + j] = b;
    }
  } else {
    if (*ecnt == 0) return;
    int p = (blockIdx.x - 1) * 256 + threadIdx.x;
    float s = 0.f;
    for (int k = 0; k < NN; ++k)
      if (empty[k]) s += W2[(size_t)p * NN + k];
    uW[p] = s * (1.0f / NN);
  }
}

// ---------------------------------------------------------------- scatter by column
__global__ void scatter_kernel(const int* __restrict__ idx, const float* __restrict__ vals,
                               int nnz, int* __restrict__ cursor,
                               int* __restrict__ ek, float* __restrict__ ev) {
  int j = blockIdx.x * blockDim.x + threadIdx.x;
  if (j >= nnz) return;
  int f = idx[j];
  int c = f & (NN - 1), r = f >> LOG2NN;
  if (c != r) {
    int p = atomicAdd(&cursor[c], 1);
    ek[p] = r;
    ev[p] = vals[j];
  }
}

// ---------------------------------------------------------------- SpMM: WfT rows
// 4 waves/block; wave handles (row n, p-half h): 1024 cols, 16/lane.
// WT holds W1^T on entry; wave reads WT[n, half] (diag term) then overwrites
// the same range with Wfused^T (region-exclusive in-place).
//   WfT[n,p] = sum_{edges(k,n)} v * W2T[k,p] + diag[n]*W1T[n,p] + uW[p]
//              - empty[n]*W2T[n,p]/NN
__global__ __launch_bounds__(256) void spmm_kernel(
    const int* __restrict__ ek, const float* __restrict__ ev,
    const int* __restrict__ base, const int* __restrict__ hist,
    const ushort* __restrict__ W2T,
    const float* __restrict__ diag, const int* __restrict__ empty,
    const float* __restrict__ uW, ushort* WT) {
  const int w = threadIdx.x >> 6, lane = threadIdx.x & 63;
  const int n = blockIdx.x * 2 + (w >> 1);
  const int c0 = (w & 1) * 1024 + lane * 16;  // groups at c0, c0+8
  const int start = base[n], cnt = hist[n];
  float acc[2][8];
#pragma unroll
  for (int g = 0; g < 2; ++g) {
    float4 u0 = *reinterpret_cast<const float4*>(&uW[c0 + g * 8]);
    float4 u1 = *reinterpret_cast<const float4*>(&uW[c0 + g * 8 + 4]);
    acc[g][0] = u0.x; acc[g][1] = u0.y; acc[g][2] = u0.z; acc[g][3] = u0.w;
    acc[g][4] = u1.x; acc[g][5] = u1.y; acc[g][6] = u1.z; acc[g][7] = u1.w;
  }
  // diag term first (reads WT range before overwriting it below)
  float d = diag[n];
  if (d != 0.f) {
#pragma unroll
    for (int g = 0; g < 2; ++g) {
      bf16x8 wd = *reinterpret_cast<const bf16x8*>(&WT[(size_t)n * NN + c0 + g * 8]);
#pragma unroll
      for (int j = 0; j < 8; ++j) acc[g][j] += d * (float)wd[j];
    }
  }
  int i = 0;
  for (; i + 4 <= cnt; i += 4) {
    int k[4];
    float v[4];
    bf16x8 wv[4][2];
#pragma unroll
    for (int e2 = 0; e2 < 4; ++e2) {
      k[e2] = ek[start + i + e2];
      v[e2] = ev[start + i + e2];
    }
#pragma unroll
    for (int e2 = 0; e2 < 4; ++e2)
#pragma unroll
      for (int g = 0; g < 2; ++g)
        wv[e2][g] = *reinterpret_cast<const bf16x8*>(&W2T[(size_t)k[e2] * NN + c0 + g * 8]);
#pragma unroll
    for (int e2 = 0; e2 < 4; ++e2)
#pragma unroll
      for (int g = 0; g < 2; ++g)
#pragma unroll
        for (int j = 0; j < 8; ++j)
          acc[g][j] += v[e2] * (float)wv[e2][g][j];
  }
  for (; i < cnt; ++i) {
    int k0 = ek[start + i];
    float v0 = ev[start + i];
#pragma unroll
    for (int g = 0; g < 2; ++g) {
      bf16x8 w0 = *reinterpret_cast<const bf16x8*>(&W2T[(size_t)k0 * NN + c0 + g * 8]);
#pragma unroll
      for (int j = 0; j < 8; ++j) acc[g][j] += v0 * (float)w0[j];
    }
  }
  if (empty[n]) {
#pragma unroll
    for (int g = 0; g < 2; ++g) {
      bf16x8 we = *reinterpret_cast<const bf16x8*>(&W2T[(size_t)n * NN + c0 + g * 8]);
#pragma unroll
      for (int j = 0; j < 8; ++j) acc[g][j] -= (1.0f / NN) * (float)we[j];
    }
  }
#pragma unroll
  for (int g = 0; g < 2; ++g) {
    uint4 o;
    o.x = (uint32_t)f2bf(acc[g][0]) | ((uint32_t)f2bf(acc[g][1]) << 16);
    o.y = (uint32_t)f2bf(acc[g][2]) | ((uint32_t)f2bf(acc[g][3]) << 16);
    o.z = (uint32_t)f2bf(acc[g][4]) | ((uint32_t)f2bf(acc[g][5]) << 16);
    o.w = (uint32_t)f2bf(acc[g][6]) | ((uint32_t)f2bf(acc[g][7]) << 16);
    *reinterpret_cast<uint4*>(&WT[(size_t)n * NN + c0 + g * 8]) = o;
  }
}

// ---------------------------------------------------------------- bf16 bt-GEMM (m97, split-K=2)
// C[row, col] += sum_{k in half z} A[row, k] * Bt[col, k]; 128x128 tile,
// 4 waves, BK=32. blockIdx.z selects the K-half; epilogue is native fp32
// atomic add onto zero-initialized C. Exactly 2 adds per address onto exact
// zero -> result independent of order (deterministic across replays).
__device__ __forceinline__ void gload_lds16(const ushort* g, char* l) {
  __builtin_amdgcn_global_load_lds(
      (__attribute__((address_space(1))) uint32_t*)(uintptr_t)g,
      (__attribute__((address_space(3))) uint32_t*)l, 16, 0, 0);
}

__global__ __launch_bounds__(256)
void gemm_bt_kernel(const ushort* __restrict__ A, const ushort* __restrict__ Bt,
                    float* __restrict__ Cf) {
  __shared__ ushort As[128 * 32];
  __shared__ ushort Bs[128 * 32];
  const int t = threadIdx.x;
  const int wid = t >> 6;
  const int lane = t & 63;
  const int m0 = blockIdx.y * 128;
  const int n0 = blockIdx.x * 128;
  const int k0 = blockIdx.z * (GK / 2);
  const int wm = wid >> 1, wn = wid & 1;

  f32x4 acc[4][4] = {};

  const ushort* Ag0 = A + (size_t)(m0 + (t >> 2)) * GK + (t & 3) * 8;
  const ushort* Ag1 = Ag0 + (size_t)64 * GK;
  const ushort* Bg0 = Bt + (size_t)(n0 + (t >> 2)) * GK + (t & 3) * 8;
  const ushort* Bg1 = Bg0 + (size_t)64 * GK;
  char* AsW = (char*)As + wid * 1024;
  char* BsW = (char*)Bs + wid * 1024;

  const int fr = lane & 15, fg = lane >> 4;
  const ushort* ArdA = As + (size_t)(wm * 64 + fr) * 32 + fg * 8;
  const ushort* ArdB = Bs + (size_t)(wn * 64 + fr) * 32 + fg * 8;

  for (int kt = k0; kt < k0 + GK / 2; kt += 32) {
    gload_lds16(Ag0 + kt, AsW);
    gload_lds16(Ag1 + kt, AsW + 4096);
    gload_lds16(Bg0 + kt, BsW);
    gload_lds16(Bg1 + kt, BsW + 4096);
    __syncthreads();
    bf16x8 af[4], bb[4];
#pragma unroll
    for (int i = 0; i < 4; ++i) af[i] = *reinterpret_cast<const bf16x8*>(ArdA + i * 16 * 32);
#pragma unroll
    for (int i = 0; i < 4; ++i) bb[i] = *reinterpret_cast<const bf16x8*>(ArdB + i * 16 * 32);
#pragma unroll
    for (int i = 0; i < 4; ++i)
#pragma unroll
      for (int j = 0; j < 4; ++j)
        acc[i][j] = __builtin_amdgcn_mfma_f32_16x16x32_bf16(af[i], bb[j], acc[i][j], 0, 0, 0);
    __syncthreads();
  }

  const int cr = lane >> 4, cc = lane & 15;
#pragma unroll
  for (int i = 0; i < 4; ++i)
#pragma unroll
    for (int j = 0; j < 4; ++j)
#pragma unroll
      for (int q = 0; q < 4; ++q) {
        int grow = m0 + wm * 64 + i * 16 + cr * 4 + q;
        int gcol = n0 + wn * 64 + j * 16 + cc;
        unsafeAtomicAdd(&Cf[(size_t)grow * GNC + gcol], acc[i][j][q]);
      }
}

// ---------------------------------------------------------------- launch
extern "C" void kernel_launch(void* const* d_in, const int* in_sizes, int n_in,
                              void* d_out, int out_size, void* d_ws, size_t ws_size,
                              hipStream_t stream) {
  const float* x   = (const float*)d_in[0];  // [8,512,2048] -> [4096][2048]
  const float* W1  = (const float*)d_in[1];  // [2048][2048]
  const float* W2  = (const float*)d_in[2];  // [2048][2048]
  const float* e   = (const float*)d_in[3];  // [nnz]
  const int*   eix = (const int*)d_in[4];    // [nnz] sorted flat indices
  const int nnz = in_sizes[3];
  float* out = (float*)d_out;                // [4096][2048] fp32

  // ws layout: 34.39 MB total — byte-identical to the round-3/4 layout that
  // passed post-timing validation. Do not grow (round-2 lesson).
  char* w = (char*)d_ws;
  ushort* W2T  = (ushort*)w; w += (size_t)NN * NN * 2;    // 8.4 MB  W2^T bf16 [k][p]
  ushort* WT   = (ushort*)w; w += (size_t)NN * NN * 2;    // 8.4 MB  W1^T then Wfused^T [n][p]
  ushort* xb   = (ushort*)w; w += (size_t)4096 * NN * 2;  // 16.8 MB x bf16 [m][p]
  float*  vals = (float*)w;  w += (size_t)nnz * 4;
  int*    ek   = (int*)w;    w += (size_t)nnz * 4;
  float*  ev   = (float*)w;  w += (size_t)nnz * 4;
  int*    hist = (int*)w;    w += NN * 4;
  int*    base = (int*)w;    w += NN * 4;
  int*    curs = (int*)w;    w += NN * 4;
  float*  diag = (float*)w;  w += NN * 4;
  int*    empt = (int*)w;    w += NN * 4;
  float*  uW   = (float*)w;  w += NN * 4;
  int*    ecnt = (int*)w;    w += 256;

  prep_kernel<<<dim3(14337), dim3(256), 0, stream>>>(W1, W2, WT, W2T, x, xb,
                                                     hist, uW, ecnt, (float4*)out);
  softmax_hist_kernel<<<dim3(512), dim3(256), 0, stream>>>(eix, e, nnz, vals,
                                                           diag, empt, ecnt, hist);
  scan_uw_kernel<<<dim3(9), dim3(256), 0, stream>>>(hist, base, curs, W2, empt,
                                                    ecnt, uW);
  scatter_kernel<<<dim3((nnz + 255) / 256), dim3(256), 0, stream>>>(eix, vals, nnz,
                                                                    curs, ek, ev);
  spmm_kernel<<<dim3(1024), dim3(256), 0, stream>>>(ek, ev, base, hist, W2T,
                                                    diag, empt, uW, WT);
  gemm_bt_kernel<<<dim3(16, 32, 2), dim3(256), 0, stream>>>(xb, WT, out);
}

// Round 6
// 125.473 us; speedup vs baseline: 1.3399x; 1.3399x over previous
//
#include <hip/hip_runtime.h>
#include <hip/hip_bf16.h>
#include <stdint.h>

#define NN 2048
#define LOG2NN 11
#define GK 2048
#define GNC 2048

typedef __bf16 bf16x8 __attribute__((ext_vector_type(8)));
typedef float f32x4 __attribute__((ext_vector_type(4)));

// round-to-nearest-even f32 -> bf16 bits
__device__ __forceinline__ ushort f2bf(float f) {
  uint32_t x = __float_as_uint(f);
  uint32_t r = (x + 0x7fffu + ((x >> 16) & 1u)) >> 16;
  return (ushort)r;
}

// ---------------------------------------------------------------- prep (fused)
// blocks [0,2048): transpose W1/W2 f32 -> bf16^T (64x64 tiles)
// blocks [2048,6144): x f32 -> bf16 (8 elems/thread)
// block 6144: zero hist/uW/ecnt
__global__ __launch_bounds__(256) void prep_kernel(
    const float* __restrict__ W1, const float* __restrict__ W2,
    ushort* __restrict__ WT, ushort* __restrict__ W2T,
    const float* __restrict__ x, ushort* __restrict__ xb,
    int* __restrict__ hist, float* __restrict__ uW, int* __restrict__ ecnt) {
  __shared__ float tile[64][65];
  const int bid = blockIdx.x;
  const int t = threadIdx.x;
  if (bid < 2048) {  // transpose: out[c][r] = (bf16) in[r][c]
    const int m = bid >> 10;            // 0 = W1, 1 = W2
    const int rem = bid & 1023;
    const int r0 = (rem >> 5) * 64, c0 = (rem & 31) * 64;
    const float* in = m ? W2 : W1;
    ushort* out = m ? W2T : WT;
    const int tx = t & 15, ty = t >> 4;
#pragma unroll
    for (int i = 0; i < 4; ++i) {
      int r = i * 16 + ty;
      float4 v = *reinterpret_cast<const float4*>(&in[(size_t)(r0 + r) * NN + c0 + tx * 4]);
      tile[r][tx * 4 + 0] = v.x;
      tile[r][tx * 4 + 1] = v.y;
      tile[r][tx * 4 + 2] = v.z;
      tile[r][tx * 4 + 3] = v.w;
    }
    __syncthreads();
#pragma unroll
    for (int i = 0; i < 4; ++i) {
      int oc = i * 16 + ty;  // output row = original col
      ushort4 o;
      o.x = f2bf(tile[tx * 4 + 0][oc]);
      o.y = f2bf(tile[tx * 4 + 1][oc]);
      o.z = f2bf(tile[tx * 4 + 2][oc]);
      o.w = f2bf(tile[tx * 4 + 3][oc]);
      *reinterpret_cast<ushort4*>(&out[(size_t)(c0 + oc) * NN + r0 + tx * 4]) = o;
    }
  } else if (bid < 6144) {  // x f32 -> bf16
    int i = (bid - 2048) * 256 + t;  // 8 floats each
    const float4* in4 = reinterpret_cast<const float4*>(x);
    float4 a = in4[2 * i];
    float4 b = in4[2 * i + 1];
    uint4 o;
    o.x = (uint32_t)f2bf(a.x) | ((uint32_t)f2bf(a.y) << 16);
    o.y = (uint32_t)f2bf(a.z) | ((uint32_t)f2bf(a.w) << 16);
    o.z = (uint32_t)f2bf(b.x) | ((uint32_t)f2bf(b.y) << 16);
    o.w = (uint32_t)f2bf(b.z) | ((uint32_t)f2bf(b.w) << 16);
    reinterpret_cast<uint4*>(xb)[i] = o;
  } else {  // init
#pragma unroll
    for (int j = 0; j < 8; ++j) {
      hist[t * 8 + j] = 0;
      uW[t * 8 + j] = 0.f;
    }
    if (t == 0) *ecnt = 0;
  }
}

// ---------------------------------------------------------------- softmax + hist (fused)
__device__ __forceinline__ int lower_bound32(const int* __restrict__ a, int n, int v) {
  int lo = 0, hi = n;
  while (lo < hi) {
    int mid = (lo + hi) >> 1;
    if (a[mid] < v) lo = mid + 1; else hi = mid;
  }
  return lo;
}

__global__ __launch_bounds__(256) void softmax_hist_kernel(
    const int* __restrict__ idx, const float* __restrict__ e, int nnz,
    float* __restrict__ vals, float* __restrict__ diag, int* __restrict__ empty,
    int* __restrict__ ecnt, int* __restrict__ hist) {
  const int w = threadIdx.x >> 6, lane = threadIdx.x & 63;
  const int r = blockIdx.x * 4 + w;
  int lo = lower_bound32(idx, nnz, r << LOG2NN);
  int hi = lower_bound32(idx, nnz, (r + 1) << LOG2NN);
  if (hi <= lo) {  // empty row: softmax of all-equal NEG -> uniform 1/NN
    if (lane == 0) { diag[r] = 1.0f / NN; empty[r] = 1; atomicAdd(ecnt, 1); }
    return;
  }
  float m = -3.0e38f;
  for (int j = lo + lane; j < hi; j += 64) m = fmaxf(m, e[j]);
#pragma unroll
  for (int s = 32; s >= 1; s >>= 1) m = fmaxf(m, __shfl_xor(m, s));
  float sum = 0.f;
  for (int j = lo + lane; j < hi; j += 64) sum += expf(e[j] - m);
#pragma unroll
  for (int s = 32; s >= 1; s >>= 1) sum += __shfl_xor(sum, s);
  float inv = 1.0f / sum;
  float dv = 0.f;
  for (int j = lo + lane; j < hi; j += 64) {
    float v = expf(e[j] - m) * inv;
    vals[j] = v;
    int c = idx[j] & (NN - 1);
    if (c == r) dv = v;
    else atomicAdd(&hist[c], 1);
  }
#pragma unroll
  for (int s = 32; s >= 1; s >>= 1) dv += __shfl_xor(dv, s);
  if (lane == 0) { diag[r] = dv; empty[r] = 0; }
}

// ---------------------------------------------------------------- scan + uw (fused)
__global__ __launch_bounds__(256) void scan_uw_kernel(
    const int* __restrict__ hist, int* __restrict__ base, int* __restrict__ cursor,
    const float* __restrict__ W2, const int* __restrict__ empty,
    const int* __restrict__ ecnt, float* __restrict__ uW) {
  if (blockIdx.x == 0) {
    const int l = threadIdx.x;
    if (l >= 64) return;
    int vals[32], pre[32];
    int run = 0;
#pragma unroll
    for (int j = 0; j < 32; ++j) {
      vals[j] = hist[l * 32 + j];
      pre[j] = run;
      run += vals[j];
    }
    int tot = run, inc = run;
#pragma unroll
    for (int s = 1; s < 64; s <<= 1) {
      int o = __shfl_up(inc, s);
      if (l >= s) inc += o;
    }
    int excl = inc - tot;
#pragma unroll
    for (int j = 0; j < 32; ++j) {
      int b = excl + pre[j];
      base[l * 32 + j] = b;
      cursor[l * 32 + j] = b;
    }
  } else {
    if (*ecnt == 0) return;
    int p = (blockIdx.x - 1) * 256 + threadIdx.x;
    float s = 0.f;
    for (int k = 0; k < NN; ++k)
      if (empty[k]) s += W2[(size_t)p * NN + k];
    uW[p] = s * (1.0f / NN);
  }
}

// ---------------------------------------------------------------- scatter by column
__global__ void scatter_kernel(const int* __restrict__ idx, const float* __restrict__ vals,
                               int nnz, int* __restrict__ cursor,
                               int* __restrict__ ek, float* __restrict__ ev) {
  int j = blockIdx.x * blockDim.x + threadIdx.x;
  if (j >= nnz) return;
  int f = idx[j];
  int c = f & (NN - 1), r = f >> LOG2NN;
  if (c != r) {
    int p = atomicAdd(&cursor[c], 1);
    ek[p] = r;
    ev[p] = vals[j];
  }
}

// ---------------------------------------------------------------- SpMM: WfT rows
__global__ __launch_bounds__(256) void spmm_kernel(
    const int* __restrict__ ek, const float* __restrict__ ev,
    const int* __restrict__ base, const int* __restrict__ hist,
    const ushort* __restrict__ W2T,
    const float* __restrict__ diag, const int* __restrict__ empty,
    const float* __restrict__ uW, ushort* WT) {
  const int w = threadIdx.x >> 6, lane = threadIdx.x & 63;
  const int n = blockIdx.x * 2 + (w >> 1);
  const int c0 = (w & 1) * 1024 + lane * 16;  // groups at c0, c0+8
  const int start = base[n], cnt = hist[n];
  float acc[2][8];
#pragma unroll
  for (int g = 0; g < 2; ++g) {
    float4 u0 = *reinterpret_cast<const float4*>(&uW[c0 + g * 8]);
    float4 u1 = *reinterpret_cast<const float4*>(&uW[c0 + g * 8 + 4]);
    acc[g][0] = u0.x; acc[g][1] = u0.y; acc[g][2] = u0.z; acc[g][3] = u0.w;
    acc[g][4] = u1.x; acc[g][5] = u1.y; acc[g][6] = u1.z; acc[g][7] = u1.w;
  }
  float d = diag[n];  // diag term first (reads WT range before overwriting)
  if (d != 0.f) {
#pragma unroll
    for (int g = 0; g < 2; ++g) {
      bf16x8 wd = *reinterpret_cast<const bf16x8*>(&WT[(size_t)n * NN + c0 + g * 8]);
#pragma unroll
      for (int j = 0; j < 8; ++j) acc[g][j] += d * (float)wd[j];
    }
  }
  int i = 0;
  for (; i + 4 <= cnt; i += 4) {
    int k[4];
    float v[4];
    bf16x8 wv[4][2];
#pragma unroll
    for (int e2 = 0; e2 < 4; ++e2) {
      k[e2] = ek[start + i + e2];
      v[e2] = ev[start + i + e2];
    }
#pragma unroll
    for (int e2 = 0; e2 < 4; ++e2)
#pragma unroll
      for (int g = 0; g < 2; ++g)
        wv[e2][g] = *reinterpret_cast<const bf16x8*>(&W2T[(size_t)k[e2] * NN + c0 + g * 8]);
#pragma unroll
    for (int e2 = 0; e2 < 4; ++e2)
#pragma unroll
      for (int g = 0; g < 2; ++g)
#pragma unroll
        for (int j = 0; j < 8; ++j)
          acc[g][j] += v[e2] * (float)wv[e2][g][j];
  }
  for (; i < cnt; ++i) {
    int k0 = ek[start + i];
    float v0 = ev[start + i];
#pragma unroll
    for (int g = 0; g < 2; ++g) {
      bf16x8 w0 = *reinterpret_cast<const bf16x8*>(&W2T[(size_t)k0 * NN + c0 + g * 8]);
#pragma unroll
      for (int j = 0; j < 8; ++j) acc[g][j] += v0 * (float)w0[j];
    }
  }
  if (empty[n]) {
#pragma unroll
    for (int g = 0; g < 2; ++g) {
      bf16x8 we = *reinterpret_cast<const bf16x8*>(&W2T[(size_t)n * NN + c0 + g * 8]);
#pragma unroll
      for (int j = 0; j < 8; ++j) acc[g][j] -= (1.0f / NN) * (float)we[j];
    }
  }
#pragma unroll
  for (int g = 0; g < 2; ++g) {
    uint4 o;
    o.x = (uint32_t)f2bf(acc[g][0]) | ((uint32_t)f2bf(acc[g][1]) << 16);
    o.y = (uint32_t)f2bf(acc[g][2]) | ((uint32_t)f2bf(acc[g][3]) << 16);
    o.z = (uint32_t)f2bf(acc[g][4]) | ((uint32_t)f2bf(acc[g][5]) << 16);
    o.w = (uint32_t)f2bf(acc[g][6]) | ((uint32_t)f2bf(acc[g][7]) << 16);
    *reinterpret_cast<uint4*>(&WT[(size_t)n * NN + c0 + g * 8]) = o;
  }
}

// ---------------------------------------------------------------- 8-phase 256^2 GEMM
// C[row,col] = sum_k A[row,k]*Bt[col,k]. BM=BN=256, BK=64, 512 thr (8 waves,
// 2M x 4N interleaved), 128KiB LDS (A,B double-buffered), XOR-swizzled LDS,
// counted vmcnt(6), setprio around MFMA clusters. Plain fp32 stores.
__device__ __forceinline__ void gload_lds16(const ushort* g, char* l) {
  __builtin_amdgcn_global_load_lds(
      (__attribute__((address_space(1))) uint32_t*)(uintptr_t)g,
      (__attribute__((address_space(3))) uint32_t*)l, 16, 0, 0);
}

#define NT 32  // K-tiles (2048/64)

__global__ __launch_bounds__(512, 2)
void gemm8_kernel(const ushort* __restrict__ A, const ushort* __restrict__ Bt,
                  float* __restrict__ Cf) {
  __shared__ __align__(16) char smem[131072];  // [A buf0|A buf1|B buf0|B buf1] 32KB each
  const int t = threadIdx.x;
  const int wid = t >> 6, lane = t & 63;
  const int wm = wid >> 2, wn = wid & 3;
  const int fr = lane & 15, fg = lane >> 4;

  // XCD-aware swizzle (128 blocks, 128%8==0 -> simple form valid)
  const int swz = ((int)blockIdx.x & 7) * 16 + ((int)blockIdx.x >> 3);
  const int m0 = (swz >> 3) * 256;
  const int n0 = (swz & 7) * 256;

  // ---- staging constants: LDS linear dest, inverse-swizzled global source.
  // LDS byte L = h*16384 + s*8192 + wid*1024 + lane*16 -> row = L>>7,
  // within-row slot swizzle: src col = ((lane&7) ^ (lane>>3)) * 16 bytes.
  const int l8 = lane >> 3;
  const int scol = ((lane & 7) ^ l8) << 3;  // elements
  const int srow = wid * 8 + l8;            // row within a 64-row (h,s) slab

#define STG(PTR, BASE0, MATOFF, H, TAU) do {                                   \
    const int _b = (TAU) & 1;                                                  \
    gload_lds16((PTR) + (size_t)((BASE0) + (H) * 128 + srow) * GK +            \
                    (TAU) * 64 + scol,                                         \
                smem + (MATOFF) + _b * 32768 + (H) * 16384 + wid * 1024);      \
    gload_lds16((PTR) + (size_t)((BASE0) + (H) * 128 + 64 + srow) * GK +       \
                    (TAU) * 64 + scol,                                         \
                smem + (MATOFF) + _b * 32768 + (H) * 16384 + 8192 + wid * 1024); \
  } while (0)

  // ---- ds_read addressing (swizzled): row R, k-slot offset ko{0,1}
  const int sw = (fr & 7) << 4;
  const int ko0 = (fg * 16) ^ sw;        // ks=0
  const int ko1 = (64 + fg * 16) ^ sw;   // ks=1
  const int arow = (wm * 16 + fr) * 128; // A row base (bytes)
  const int brow = (wn * 32 + fr) * 128; // B row base (bytes)

  f32x4 acc[2][2][4][2] = {};
  bf16x8 aF[4][2], b0F[2][2], b1F[2][2];

#define LDA(MQ, B_) do {                                                       \
    _Pragma("unroll") for (int mf = 0; mf < 4; ++mf) {                         \
      const char* _p = smem + (B_) * 32768 + arow + ((MQ) * 128 + mf * 32) * 128; \
      aF[mf][0] = *reinterpret_cast<const bf16x8*>(_p + ko0);                  \
      aF[mf][1] = *reinterpret_cast<const bf16x8*>(_p + ko1);                  \
    }                                                                          \
  } while (0)

#define LDB(DST, NQ, B_) do {                                                  \
    _Pragma("unroll") for (int nf = 0; nf < 2; ++nf) {                         \
      const char* _p = smem + 65536 + (B_) * 32768 + brow +                    \
                       ((NQ) * 128 + nf * 16) * 128;                           \
      DST[nf][0] = *reinterpret_cast<const bf16x8*>(_p + ko0);                 \
      DST[nf][1] = *reinterpret_cast<const bf16x8*>(_p + ko1);                 \
    }                                                                          \
  } while (0)

#define MM(MQ, NQ, BF) do {                                                    \
    _Pragma("unroll") for (int mf = 0; mf < 4; ++mf)                           \
      _Pragma("unroll") for (int nf = 0; nf < 2; ++nf) {                       \
        acc[MQ][NQ][mf][nf] = __builtin_amdgcn_mfma_f32_16x16x32_bf16(         \
            aF[mf][0], BF[nf][0], acc[MQ][NQ][mf][nf], 0, 0, 0);               \
        acc[MQ][NQ][mf][nf] = __builtin_amdgcn_mfma_f32_16x16x32_bf16(         \
            aF[mf][1], BF[nf][1], acc[MQ][NQ][mf][nf], 0, 0, 0);               \
      }                                                                        \
  } while (0)

#define PHASE_MID() do {                                                       \
    __builtin_amdgcn_s_barrier();                                              \
    asm volatile("s_waitcnt lgkmcnt(0)" ::: "memory");                         \
    __builtin_amdgcn_sched_barrier(0);                                         \
    __builtin_amdgcn_s_setprio(1);                                             \
  } while (0)

#define PHASE_END() do {                                                       \
    __builtin_amdgcn_s_setprio(0);                                             \
    __builtin_amdgcn_s_barrier();                                              \
  } while (0)

  // ---- prologue: A0,B0,A1,B1 of tile0; A0,B0,A1 of tile1 (7 half-tiles)
  STG(A, m0, 0, 0, 0);      STG(Bt, n0, 65536, 0, 0);
  STG(A, m0, 0, 1, 0);      STG(Bt, n0, 65536, 1, 0);
  STG(A, m0, 0, 0, 1);      STG(Bt, n0, 65536, 0, 1);
  STG(A, m0, 0, 1, 1);
  asm volatile("s_waitcnt vmcnt(6)" ::: "memory");   // tile0 fully landed
  __builtin_amdgcn_sched_barrier(0);
  __builtin_amdgcn_s_barrier();

  for (int kt = 0; kt < NT; ++kt) {
    const int b = kt & 1;
    const int t1 = (kt + 1) & (NT - 1), t2 = (kt + 2) & (NT - 1);
    // ph1 (mq0,nq0): read A0+B0; stage B1(t+1) -> other buf
    LDA(0, b); LDB(b0F, 0, b);
    STG(Bt, n0, 65536, 1, t1);
    PHASE_MID(); MM(0, 0, b0F); PHASE_END();
    // ph2 (mq0,nq1): read B1; stage A0(t+2) (A0 reads done ph1)
    LDB(b1F, 1, b);
    STG(A, m0, 0, 0, t2);
    PHASE_MID(); MM(0, 1, b1F); PHASE_END();
    // ph3 (mq1,nq0): read A1; stage B0(t+2) (B0 reads done ph1)
    LDA(1, b);
    STG(Bt, n0, 65536, 0, t2);
    PHASE_MID(); MM(1, 0, b0F); PHASE_END();
    // ph4 (mq1,nq1): all regs; stage A1(t+2) (A1 reads done ph3)
    STG(A, m0, 0, 1, t2);
    PHASE_MID(); MM(1, 1, b1F);
    __builtin_amdgcn_s_setprio(0);
    asm volatile("s_waitcnt vmcnt(6)" ::: "memory");  // tile t+1 fully landed
    __builtin_amdgcn_sched_barrier(0);
    __builtin_amdgcn_s_barrier();
  }

  asm volatile("s_waitcnt vmcnt(0)" ::: "memory");  // drain tail stages
  const int cr = lane >> 4, cc = lane & 15;
#pragma unroll
  for (int mq = 0; mq < 2; ++mq)
#pragma unroll
    for (int nq = 0; nq < 2; ++nq)
#pragma unroll
      for (int mf = 0; mf < 4; ++mf)
#pragma unroll
        for (int nf = 0; nf < 2; ++nf)
#pragma unroll
          for (int q = 0; q < 4; ++q) {
            int gm = m0 + mq * 128 + mf * 32 + wm * 16 + cr * 4 + q;
            int gn = n0 + nq * 128 + wn * 32 + nf * 16 + cc;
            Cf[(size_t)gm * GNC + gn] = acc[mq][nq][mf][nf][q];
          }
}

// ---------------------------------------------------------------- launch
extern "C" void kernel_launch(void* const* d_in, const int* in_sizes, int n_in,
                              void* d_out, int out_size, void* d_ws, size_t ws_size,
                              hipStream_t stream) {
  const float* x   = (const float*)d_in[0];  // [8,512,2048] -> [4096][2048]
  const float* W1  = (const float*)d_in[1];  // [2048][2048]
  const float* W2  = (const float*)d_in[2];  // [2048][2048]
  const float* e   = (const float*)d_in[3];  // [nnz]
  const int*   eix = (const int*)d_in[4];    // [nnz] sorted flat indices
  const int nnz = in_sizes[3];
  float* out = (float*)d_out;                // [4096][2048] fp32

  // ws layout: 34.39 MB total — byte-identical to the round-3/4 layout that
  // passed post-timing validation. Do not grow (round-2 lesson).
  char* w = (char*)d_ws;
  ushort* W2T  = (ushort*)w; w += (size_t)NN * NN * 2;    // 8.4 MB  W2^T bf16 [k][p]
  ushort* WT   = (ushort*)w; w += (size_t)NN * NN * 2;    // 8.4 MB  W1^T then Wfused^T [n][p]
  ushort* xb   = (ushort*)w; w += (size_t)4096 * NN * 2;  // 16.8 MB x bf16 [m][p]
  float*  vals = (float*)w;  w += (size_t)nnz * 4;
  int*    ek   = (int*)w;    w += (size_t)nnz * 4;
  float*  ev   = (float*)w;  w += (size_t)nnz * 4;
  int*    hist = (int*)w;    w += NN * 4;
  int*    base = (int*)w;    w += NN * 4;
  int*    curs = (int*)w;    w += NN * 4;
  float*  diag = (float*)w;  w += NN * 4;
  int*    empt = (int*)w;    w += NN * 4;
  float*  uW   = (float*)w;  w += NN * 4;
  int*    ecnt = (int*)w;    w += 256;

  prep_kernel<<<dim3(6145), dim3(256), 0, stream>>>(W1, W2, WT, W2T, x, xb,
                                                    hist, uW, ecnt);
  softmax_hist_kernel<<<dim3(512), dim3(256), 0, stream>>>(eix, e, nnz, vals,
                                                           diag, empt, ecnt, hist);
  scan_uw_kernel<<<dim3(9), dim3(256), 0, stream>>>(hist, base, curs, W2, empt,
                                                    ecnt, uW);
  scatter_kernel<<<dim3((nnz + 255) / 256), dim3(256), 0, stream>>>(eix, vals, nnz,
                                                                    curs, ek, ev);
  spmm_kernel<<<dim3(1024), dim3(256), 0, stream>>>(ek, ev, base, hist, W2T,
                                                    diag, empt, uW, WT);
  gemm8_kernel<<<dim3(128), dim3(512), 0, stream>>>(xb, WT, out);
}

// Round 7
// 109.676 us; speedup vs baseline: 1.5329x; 1.1440x over previous
//
#include <hip/hip_runtime.h>
#include <hip/hip_bf16.h>
#include <stdint.h>

#define NN 2048
#define LOG2NN 11
#define GK 2048
#define GNC 2048

typedef __bf16 bf16x8 __attribute__((ext_vector_type(8)));
typedef float f32x4 __attribute__((ext_vector_type(4)));

// round-to-nearest-even f32 -> bf16 bits
__device__ __forceinline__ ushort f2bf(float f) {
  uint32_t x = __float_as_uint(f);
  uint32_t r = (x + 0x7fffu + ((x >> 16) & 1u)) >> 16;
  return (ushort)r;
}

// ---------------------------------------------------------------- prep (fused)
__global__ __launch_bounds__(256) void prep_kernel(
    const float* __restrict__ W1, const float* __restrict__ W2,
    ushort* __restrict__ WT, ushort* __restrict__ W2T,
    const float* __restrict__ x, ushort* __restrict__ xb,
    int* __restrict__ hist, float* __restrict__ uW, int* __restrict__ ecnt) {
  __shared__ float tile[64][65];
  const int bid = blockIdx.x;
  const int t = threadIdx.x;
  if (bid < 2048) {  // transpose: out[c][r] = (bf16) in[r][c]
    const int m = bid >> 10;            // 0 = W1, 1 = W2
    const int rem = bid & 1023;
    const int r0 = (rem >> 5) * 64, c0 = (rem & 31) * 64;
    const float* in = m ? W2 : W1;
    ushort* out = m ? W2T : WT;
    const int tx = t & 15, ty = t >> 4;
#pragma unroll
    for (int i = 0; i < 4; ++i) {
      int r = i * 16 + ty;
      float4 v = *reinterpret_cast<const float4*>(&in[(size_t)(r0 + r) * NN + c0 + tx * 4]);
      tile[r][tx * 4 + 0] = v.x;
      tile[r][tx * 4 + 1] = v.y;
      tile[r][tx * 4 + 2] = v.z;
      tile[r][tx * 4 + 3] = v.w;
    }
    __syncthreads();
#pragma unroll
    for (int i = 0; i < 4; ++i) {
      int oc = i * 16 + ty;  // output row = original col
      ushort4 o;
      o.x = f2bf(tile[tx * 4 + 0][oc]);
      o.y = f2bf(tile[tx * 4 + 1][oc]);
      o.z = f2bf(tile[tx * 4 + 2][oc]);
      o.w = f2bf(tile[tx * 4 + 3][oc]);
      *reinterpret_cast<ushort4*>(&out[(size_t)(c0 + oc) * NN + r0 + tx * 4]) = o;
    }
  } else if (bid < 6144) {  // x f32 -> bf16
    int i = (bid - 2048) * 256 + t;  // 8 floats each
    const float4* in4 = reinterpret_cast<const float4*>(x);
    float4 a = in4[2 * i];
    float4 b = in4[2 * i + 1];
    uint4 o;
    o.x = (uint32_t)f2bf(a.x) | ((uint32_t)f2bf(a.y) << 16);
    o.y = (uint32_t)f2bf(a.z) | ((uint32_t)f2bf(a.w) << 16);
    o.z = (uint32_t)f2bf(b.x) | ((uint32_t)f2bf(b.y) << 16);
    o.w = (uint32_t)f2bf(b.z) | ((uint32_t)f2bf(b.w) << 16);
    reinterpret_cast<uint4*>(xb)[i] = o;
  } else {  // init
#pragma unroll
    for (int j = 0; j < 8; ++j) {
      hist[t * 8 + j] = 0;
      uW[t * 8 + j] = 0.f;
    }
    if (t == 0) *ecnt = 0;
  }
}

// ---------------------------------------------------------------- softmax + hist (fused)
__device__ __forceinline__ int lower_bound32(const int* __restrict__ a, int n, int v) {
  int lo = 0, hi = n;
  while (lo < hi) {
    int mid = (lo + hi) >> 1;
    if (a[mid] < v) lo = mid + 1; else hi = mid;
  }
  return lo;
}

__global__ __launch_bounds__(256) void softmax_hist_kernel(
    const int* __restrict__ idx, const float* __restrict__ e, int nnz,
    float* __restrict__ vals, float* __restrict__ diag, int* __restrict__ empty,
    int* __restrict__ ecnt, int* __restrict__ hist) {
  const int w = threadIdx.x >> 6, lane = threadIdx.x & 63;
  const int r = blockIdx.x * 4 + w;
  int lo = lower_bound32(idx, nnz, r << LOG2NN);
  int hi = lower_bound32(idx, nnz, (r + 1) << LOG2NN);
  if (hi <= lo) {  // empty row: softmax of all-equal NEG -> uniform 1/NN
    if (lane == 0) { diag[r] = 1.0f / NN; empty[r] = 1; atomicAdd(ecnt, 1); }
    return;
  }
  float m = -3.0e38f;
  for (int j = lo + lane; j < hi; j += 64) m = fmaxf(m, e[j]);
#pragma unroll
  for (int s = 32; s >= 1; s >>= 1) m = fmaxf(m, __shfl_xor(m, s));
  float sum = 0.f;
  for (int j = lo + lane; j < hi; j += 64) sum += expf(e[j] - m);
#pragma unroll
  for (int s = 32; s >= 1; s >>= 1) sum += __shfl_xor(sum, s);
  float inv = 1.0f / sum;
  float dv = 0.f;
  for (int j = lo + lane; j < hi; j += 64) {
    float v = expf(e[j] - m) * inv;
    vals[j] = v;
    int c = idx[j] & (NN - 1);
    if (c == r) dv = v;
    else atomicAdd(&hist[c], 1);
  }
#pragma unroll
  for (int s = 32; s >= 1; s >>= 1) dv += __shfl_xor(dv, s);
  if (lane == 0) { diag[r] = dv; empty[r] = 0; }
}

// ---------------------------------------------------------------- scan + uw (fused)
__global__ __launch_bounds__(256) void scan_uw_kernel(
    const int* __restrict__ hist, int* __restrict__ base, int* __restrict__ cursor,
    const float* __restrict__ W2, const int* __restrict__ empty,
    const int* __restrict__ ecnt, float* __restrict__ uW) {
  if (blockIdx.x == 0) {
    const int l = threadIdx.x;
    if (l >= 64) return;
    int vals[32], pre[32];
    int run = 0;
#pragma unroll
    for (int j = 0; j < 32; ++j) {
      vals[j] = hist[l * 32 + j];
      pre[j] = run;
      run += vals[j];
    }
    int tot = run, inc = run;
#pragma unroll
    for (int s = 1; s < 64; s <<= 1) {
      int o = __shfl_up(inc, s);
      if (l >= s) inc += o;
    }
    int excl = inc - tot;
#pragma unroll
    for (int j = 0; j < 32; ++j) {
      int b = excl + pre[j];
      base[l * 32 + j] = b;
      cursor[l * 32 + j] = b;
    }
  } else {
    if (*ecnt == 0) return;
    int p = (blockIdx.x - 1) * 256 + threadIdx.x;
    float s = 0.f;
    for (int k = 0; k < NN; ++k)
      if (empty[k]) s += W2[(size_t)p * NN + k];
    uW[p] = s * (1.0f / NN);
  }
}

// ---------------------------------------------------------------- scatter by column
__global__ void scatter_kernel(const int* __restrict__ idx, const float* __restrict__ vals,
                               int nnz, int* __restrict__ cursor,
                               int* __restrict__ ek, float* __restrict__ ev) {
  int j = blockIdx.x * blockDim.x + threadIdx.x;
  if (j >= nnz) return;
  int f = idx[j];
  int c = f & (NN - 1), r = f >> LOG2NN;
  if (c != r) {
    int p = atomicAdd(&cursor[c], 1);
    ek[p] = r;
    ev[p] = vals[j];
  }
}

// ---------------------------------------------------------------- SpMM: WfT rows
__global__ __launch_bounds__(256) void spmm_kernel(
    const int* __restrict__ ek, const float* __restrict__ ev,
    const int* __restrict__ base, const int* __restrict__ hist,
    const ushort* __restrict__ W2T,
    const float* __restrict__ diag, const int* __restrict__ empty,
    const float* __restrict__ uW, ushort* WT) {
  const int w = threadIdx.x >> 6, lane = threadIdx.x & 63;
  const int n = blockIdx.x * 2 + (w >> 1);
  const int c0 = (w & 1) * 1024 + lane * 16;  // groups at c0, c0+8
  const int start = base[n], cnt = hist[n];
  float acc[2][8];
#pragma unroll
  for (int g = 0; g < 2; ++g) {
    float4 u0 = *reinterpret_cast<const float4*>(&uW[c0 + g * 8]);
    float4 u1 = *reinterpret_cast<const float4*>(&uW[c0 + g * 8 + 4]);
    acc[g][0] = u0.x; acc[g][1] = u0.y; acc[g][2] = u0.z; acc[g][3] = u0.w;
    acc[g][4] = u1.x; acc[g][5] = u1.y; acc[g][6] = u1.z; acc[g][7] = u1.w;
  }
  float d = diag[n];  // diag term first (reads WT range before overwriting)
  if (d != 0.f) {
#pragma unroll
    for (int g = 0; g < 2; ++g) {
      bf16x8 wd = *reinterpret_cast<const bf16x8*>(&WT[(size_t)n * NN + c0 + g * 8]);
#pragma unroll
      for (int j = 0; j < 8; ++j) acc[g][j] += d * (float)wd[j];
    }
  }
  int i = 0;
  for (; i + 4 <= cnt; i += 4) {
    int k[4];
    float v[4];
    bf16x8 wv[4][2];
#pragma unroll
    for (int e2 = 0; e2 < 4; ++e2) {
      k[e2] = ek[start + i + e2];
      v[e2] = ev[start + i + e2];
    }
#pragma unroll
    for (int e2 = 0; e2 < 4; ++e2)
#pragma unroll
      for (int g = 0; g < 2; ++g)
        wv[e2][g] = *reinterpret_cast<const bf16x8*>(&W2T[(size_t)k[e2] * NN + c0 + g * 8]);
#pragma unroll
    for (int e2 = 0; e2 < 4; ++e2)
#pragma unroll
      for (int g = 0; g < 2; ++g)
#pragma unroll
        for (int j = 0; j < 8; ++j)
          acc[g][j] += v[e2] * (float)wv[e2][g][j];
  }
  for (; i < cnt; ++i) {
    int k0 = ek[start + i];
    float v0 = ev[start + i];
#pragma unroll
    for (int g = 0; g < 2; ++g) {
      bf16x8 w0 = *reinterpret_cast<const bf16x8*>(&W2T[(size_t)k0 * NN + c0 + g * 8]);
#pragma unroll
      for (int j = 0; j < 8; ++j) acc[g][j] += v0 * (float)w0[j];
    }
  }
  if (empty[n]) {
#pragma unroll
    for (int g = 0; g < 2; ++g) {
      bf16x8 we = *reinterpret_cast<const bf16x8*>(&W2T[(size_t)n * NN + c0 + g * 8]);
#pragma unroll
      for (int j = 0; j < 8; ++j) acc[g][j] -= (1.0f / NN) * (float)we[j];
    }
  }
#pragma unroll
  for (int g = 0; g < 2; ++g) {
    uint4 o;
    o.x = (uint32_t)f2bf(acc[g][0]) | ((uint32_t)f2bf(acc[g][1]) << 16);
    o.y = (uint32_t)f2bf(acc[g][2]) | ((uint32_t)f2bf(acc[g][3]) << 16);
    o.z = (uint32_t)f2bf(acc[g][4]) | ((uint32_t)f2bf(acc[g][5]) << 16);
    o.w = (uint32_t)f2bf(acc[g][6]) | ((uint32_t)f2bf(acc[g][7]) << 16);
    *reinterpret_cast<uint4*>(&WT[(size_t)n * NN + c0 + g * 8]) = o;
  }
}

// ---------------------------------------------------------------- 256x128 pipelined GEMM
// C[row,col] = sum_k A[row,k]*Bt[col,k]. BM=256, BN=128, BK=64, 512 thr
// (8 waves, 2M x 4N), 96KiB LDS double-buffered, XOR-swizzled, counted
// vmcnt(4), setprio around MFMA. Grid 16x16 = 256 blocks = 1/CU (all CUs).
__device__ __forceinline__ void gload_lds16(const ushort* g, char* l) {
  __builtin_amdgcn_global_load_lds(
      (__attribute__((address_space(1))) uint32_t*)(uintptr_t)g,
      (__attribute__((address_space(3))) uint32_t*)l, 16, 0, 0);
}

#define NT 32  // K-tiles (2048/64)

__global__ __launch_bounds__(512, 2)
void gemm8_kernel(const ushort* __restrict__ A, const ushort* __restrict__ Bt,
                  float* __restrict__ Cf) {
  __shared__ __align__(16) char smem[98304];  // A: 2x32KB @0 | B: 2x16KB @64KB
  const int t = threadIdx.x;
  const int wid = t >> 6, lane = t & 63;
  const int wm = wid >> 2, wn = wid & 3;
  const int fr = lane & 15, fg = lane >> 4;

  // XCD-aware swizzle (256 blocks, 256%8==0 -> simple form bijective)
  const int swz = ((int)blockIdx.x & 7) * 32 + ((int)blockIdx.x >> 3);
  const int m0 = (swz >> 4) * 256;
  const int n0 = (swz & 15) * 128;

  // staging: LDS linear dest (base + lane*16 by HW), inverse-swizzled source
  const int l8 = lane >> 3;
  const int scol = ((lane & 7) ^ l8) << 3;  // source col (elements)
  const int srow = wid * 8 + l8;            // row within a 64-row slab

#define STGA(H, TAU) do {                                                      \
    const int _b = (TAU) & 1;                                                  \
    gload_lds16(A + (size_t)(m0 + (H) * 128 + srow) * GK + (TAU) * 64 + scol,  \
                smem + _b * 32768 + (H) * 16384 + wid * 1024);                 \
    gload_lds16(A + (size_t)(m0 + (H) * 128 + 64 + srow) * GK + (TAU) * 64 + scol, \
                smem + _b * 32768 + (H) * 16384 + 8192 + wid * 1024);          \
  } while (0)

#define STGB(TAU) do {                                                         \
    const int _b = (TAU) & 1;                                                  \
    gload_lds16(Bt + (size_t)(n0 + srow) * GK + (TAU) * 64 + scol,             \
                smem + 65536 + _b * 16384 + wid * 1024);                       \
    gload_lds16(Bt + (size_t)(n0 + 64 + srow) * GK + (TAU) * 64 + scol,        \
                smem + 65536 + _b * 16384 + 8192 + wid * 1024);                \
  } while (0)

  // ds_read addressing (swizzled)
  const int sw = (fr & 7) << 4;
  const int ko0 = (fg * 16) ^ sw;        // ks=0
  const int ko1 = (64 + fg * 16) ^ sw;   // ks=1
  const int arow = (wm * 16 + fr) * 128; // A row base (bytes)
  const int brow = (wn * 32 + fr) * 128; // B row base (bytes)

  f32x4 acc[2][4][2] = {};
  bf16x8 aF[4][2], bF[2][2];

#define LDA(MQ, B_) do {                                                       \
    _Pragma("unroll") for (int mf = 0; mf < 4; ++mf) {                         \
      const char* _p = smem + (B_) * 32768 + arow + ((MQ) * 128 + mf * 32) * 128; \
      aF[mf][0] = *reinterpret_cast<const bf16x8*>(_p + ko0);                  \
      aF[mf][1] = *reinterpret_cast<const bf16x8*>(_p + ko1);                  \
    }                                                                          \
  } while (0)

#define LDB(B_) do {                                                           \
    _Pragma("unroll") for (int nf = 0; nf < 2; ++nf) {                         \
      const char* _p = smem + 65536 + (B_) * 16384 + brow + (nf * 16) * 128;   \
      bF[nf][0] = *reinterpret_cast<const bf16x8*>(_p + ko0);                  \
      bF[nf][1] = *reinterpret_cast<const bf16x8*>(_p + ko1);                  \
    }                                                                          \
  } while (0)

#define MM(MQ) do {                                                            \
    _Pragma("unroll") for (int mf = 0; mf < 4; ++mf)                           \
      _Pragma("unroll") for (int nf = 0; nf < 2; ++nf) {                       \
        acc[MQ][mf][nf] = __builtin_amdgcn_mfma_f32_16x16x32_bf16(             \
            aF[mf][0], bF[nf][0], acc[MQ][mf][nf], 0, 0, 0);                   \
        acc[MQ][mf][nf] = __builtin_amdgcn_mfma_f32_16x16x32_bf16(             \
            aF[mf][1], bF[nf][1], acc[MQ][mf][nf], 0, 0, 0);                   \
      }                                                                        \
  } while (0)

#define PHASE_MID() do {                                                       \
    __builtin_amdgcn_s_barrier();                                              \
    asm volatile("s_waitcnt lgkmcnt(0)" ::: "memory");                         \
    __builtin_amdgcn_sched_barrier(0);                                         \
    __builtin_amdgcn_s_setprio(1);                                             \
  } while (0)

#define PHASE_END() do {                                                       \
    __builtin_amdgcn_s_setprio(0);                                             \
    __builtin_amdgcn_s_barrier();                                              \
  } while (0)

  // prologue: tile0 complete (6 gloads) + tile1 B,A-lo (4 gloads)
  STGA(0, 0); STGA(1, 0); STGB(0);
  STGB(1); STGA(0, 1);
  asm volatile("s_waitcnt vmcnt(4)" ::: "memory");   // tile0 landed
  __builtin_amdgcn_sched_barrier(0);
  __builtin_amdgcn_s_barrier();

  for (int kt = 0; kt < NT; ++kt) {
    const int b = kt & 1;
    const int t1 = (kt + 1) & (NT - 1), t2 = (kt + 2) & (NT - 1);
    // ph1: read A-lo + B of buf b; stage A-hi(t+1) (other buf; its readers
    //      drained before this tile's start barrier)
    LDA(0, b); LDB(b);
    STGA(1, t1);
    PHASE_MID(); MM(0); PHASE_END();
    // ph2: read A-hi of buf b; stage B(t+2), A-lo(t+2) (same buf b, but those
    //      regions' reads completed in ph1, sealed by ph1's end barrier)
    LDA(1, b);
    STGB(t2); STGA(0, t2);
    PHASE_MID(); MM(1);
    __builtin_amdgcn_s_setprio(0);
    // need tile t+1 fully landed; 4 younger gloads (t+2's B,A-lo) stay in flight
    asm volatile("s_waitcnt vmcnt(4)" ::: "memory");
    __builtin_amdgcn_sched_barrier(0);
    __builtin_amdgcn_s_barrier();
  }

  asm volatile("s_waitcnt vmcnt(0)" ::: "memory");  // drain tail stages
  const int cr = lane >> 4, cc = lane & 15;
#pragma unroll
  for (int mq = 0; mq < 2; ++mq)
#pragma unroll
    for (int mf = 0; mf < 4; ++mf)
#pragma unroll
      for (int nf = 0; nf < 2; ++nf)
#pragma unroll
        for (int q = 0; q < 4; ++q) {
          int gm = m0 + mq * 128 + mf * 32 + wm * 16 + cr * 4 + q;
          int gn = n0 + wn * 32 + nf * 16 + cc;
          Cf[(size_t)gm * GNC + gn] = acc[mq][mf][nf][q];
        }
}

// ---------------------------------------------------------------- launch
extern "C" void kernel_launch(void* const* d_in, const int* in_sizes, int n_in,
                              void* d_out, int out_size, void* d_ws, size_t ws_size,
                              hipStream_t stream) {
  const float* x   = (const float*)d_in[0];  // [8,512,2048] -> [4096][2048]
  const float* W1  = (const float*)d_in[1];  // [2048][2048]
  const float* W2  = (const float*)d_in[2];  // [2048][2048]
  const float* e   = (const float*)d_in[3];  // [nnz]
  const int*   eix = (const int*)d_in[4];    // [nnz] sorted flat indices
  const int nnz = in_sizes[3];
  float* out = (float*)d_out;                // [4096][2048] fp32

  // ws layout: 34.39 MB total — byte-identical to the round-3/4/6 layout that
  // passed post-timing validation. Do not grow (round-2 lesson).
  char* w = (char*)d_ws;
  ushort* W2T  = (ushort*)w; w += (size_t)NN * NN * 2;    // 8.4 MB  W2^T bf16 [k][p]
  ushort* WT   = (ushort*)w; w += (size_t)NN * NN * 2;    // 8.4 MB  W1^T then Wfused^T [n][p]
  ushort* xb   = (ushort*)w; w += (size_t)4096 * NN * 2;  // 16.8 MB x bf16 [m][p]
  float*  vals = (float*)w;  w += (size_t)nnz * 4;
  int*    ek   = (int*)w;    w += (size_t)nnz * 4;
  float*  ev   = (float*)w;  w += (size_t)nnz * 4;
  int*    hist = (int*)w;    w += NN * 4;
  int*    base = (int*)w;    w += NN * 4;
  int*    curs = (int*)w;    w += NN * 4;
  float*  diag = (float*)w;  w += NN * 4;
  int*    empt = (int*)w;    w += NN * 4;
  float*  uW   = (float*)w;  w += NN * 4;
  int*    ecnt = (int*)w;    w += 256;

  prep_kernel<<<dim3(6145), dim3(256), 0, stream>>>(W1, W2, WT, W2T, x, xb,
                                                    hist, uW, ecnt);
  softmax_hist_kernel<<<dim3(512), dim3(256), 0, stream>>>(eix, e, nnz, vals,
                                                           diag, empt, ecnt, hist);
  scan_uw_kernel<<<dim3(9), dim3(256), 0, stream>>>(hist, base, curs, W2, empt,
                                                    ecnt, uW);
  scatter_kernel<<<dim3((nnz + 255) / 256), dim3(256), 0, stream>>>(eix, vals, nnz,
                                                                    curs, ek, ev);
  spmm_kernel<<<dim3(1024), dim3(256), 0, stream>>>(ek, ev, base, hist, W2T,
                                                    diag, empt, uW, WT);
  gemm8_kernel<<<dim3(256), dim3(512), 0, stream>>>(xb, WT, out);
}